// Round 19
// baseline (131.443 us; speedup 1.0000x reference)
//
#include <hip/hip_runtime.h>
#include <hip/hip_bf16.h>

#define BATCH 32
#define SEQ   2048
#define EMB   1024
#define HS    64
#define BT    (BATCH*SEQ)   // 65536 rows

typedef short s16x4 __attribute__((ext_vector_type(4)));
typedef short s16x8 __attribute__((ext_vector_type(8)));
typedef float f32x4 __attribute__((ext_vector_type(4)));
using u16 = unsigned short;

static __device__ __forceinline__ short f2bf(float f) {
  __hip_bfloat16 h = __float2bfloat16(f);
  return *reinterpret_cast<short*>(&h);
}
static __device__ __forceinline__ void gl_lds16(const void* g, void* l) {
  __builtin_amdgcn_global_load_lds(
      (const __attribute__((address_space(1))) unsigned int*)g,
      (__attribute__((address_space(3))) unsigned int*)l, 16, 0, 0);
}

#define MFMA __builtin_amdgcn_mfma_f32_16x16x32_bf16

// ---------------------------------------------------------------------------
// W -> bf16, transposed: Wt[n][k], n = w*64+h (Wk|Wq|Wv). 768 KB once.
// ---------------------------------------------------------------------------
__global__ __launch_bounds__(256) void wconv_kernel(
    const float* __restrict__ Wk, const float* __restrict__ Wq,
    const float* __restrict__ Wv, short* __restrict__ Wt)
{
  const int n = blockIdx.x;            // 0..191
  const int w = n >> 6, h = n & 63;
  const float* Wp = (w == 0) ? Wk : (w == 1) ? Wq : Wv;
  const int k0 = threadIdx.x * 4;
  s16x4 p;
  #pragma unroll
  for (int e = 0; e < 4; ++e) p[e] = f2bf(Wp[(size_t)(k0 + e) * HS + h]);
  *(s16x4*)(Wt + (size_t)n * EMB + k0) = p;
}

// ---------------------------------------------------------------------------
// Projection v5: T3-minimal pipeline (the pattern that worked for attn in
// R15/16). x staged as RAW FP32 via global_load_lds into double-buffered LDS
// (cvt fp32->bf16 moved to fragment-read time; compiler fuses to cvt_pk).
// One barrier per K-step. Issue order: bw (L2) first, then gl_lds stage of
// k+1 -- in-order vmcnt => MFMA's bw-wait is vmcnt(4), stage stays in
// flight through the whole compute phase; the barrier's vmcnt(0) drain
// lands a full phase after issue. Global-source chunk swizzle
// ch ^ ((row&7)<<1) keeps fragment ds_reads at <=4-way conflict.
// Nothing held in registers across barriers (R12's spill mistake avoided).
// LDS 32 KB -> 4 blocks/CU.
// ---------------------------------------------------------------------------
__global__ __launch_bounds__(256, 4) void proj_kernel(
    const float* __restrict__ x, const short* __restrict__ Wt,
    short* __restrict__ kb, short* __restrict__ qb, short* __restrict__ vt)
{
  __shared__ __align__(16) float xsf[2][64*64];   // fp32 x, chunk-swizzled
  const int tid  = threadIdx.x;
  const int row0 = blockIdx.x * 64;
  const int w  = tid >> 6, l = tid & 63;
  const int lr = l & 15, lg = l >> 4;

  // staging: slot = i*256+tid; row = slot>>4, chunk = slot&15 (16B chunks,
  // 16/row). LDS dest linear (wave-uniform base + lane*16B); global source
  // chunk pre-swizzled: gch = ch ^ ((row&7)<<1)  (even XOR keeps 32B pairs
  // adjacent for the fragment reads).
#define STAGEX(BUF, K0) do {                                                   \
    _Pragma("unroll") for (int i = 0; i < 4; ++i) {                            \
      const int slot = i*256 + tid;                                            \
      const int srow = slot >> 4, sch = slot & 15;                             \
      const int gch  = sch ^ ((srow & 7) << 1);                                \
      gl_lds16(x + (size_t)(row0 + srow) * EMB + (K0) + gch*4,                 \
               &xsf[BUF][(i*256 + w*64) * 4]);                                 \
    }                                                                          \
  } while (0)

  f32x4 acc[4][3];
  #pragma unroll
  for (int m = 0; m < 4; ++m)
    #pragma unroll
    for (int n = 0; n < 3; ++n) acc[m][n] = f32x4{0.f, 0.f, 0.f, 0.f};

  STAGEX(0, 0);
  __syncthreads();   // prologue stage drained (one exposed latency)

  int cur = 0;
  #pragma unroll 1
  for (int k0 = 0; k0 < EMB; k0 += 64) {
    // W frags for THIS step (L2-resident) -- issued FIRST
    s16x8 bw[2][3];
    #pragma unroll
    for (int kk = 0; kk < 2; ++kk)
      #pragma unroll
      for (int n = 0; n < 3; ++n)
        bw[kk][n] = *(const s16x8*)(Wt + (size_t)(w*48 + n*16 + lr) * EMB + k0 + kk*32 + lg*8);
    // next x tile -> other LDS buffer, in flight through compute
    if (k0 + 64 < EMB) STAGEX(cur ^ 1, k0 + 64);
    // fragments from xsf[cur]: fp32 read + cvt -> bf16 a-frag
    #pragma unroll
    for (int kk = 0; kk < 2; ++kk) {
      s16x8 a[4];
      #pragma unroll
      for (int m = 0; m < 4; ++m) {
        const int row = m*16 + lr;
        const int p0  = (kk*8 + lg*2) ^ ((row & 7) << 1);
        const float* xp = &xsf[cur][row*64 + p0*4];
        f32x4 xa = *(const f32x4*)xp;
        f32x4 xb = *(const f32x4*)(xp + 4);
        s16x8 av;
        av[0]=f2bf(xa[0]); av[1]=f2bf(xa[1]); av[2]=f2bf(xa[2]); av[3]=f2bf(xa[3]);
        av[4]=f2bf(xb[0]); av[5]=f2bf(xb[1]); av[6]=f2bf(xb[2]); av[7]=f2bf(xb[3]);
        a[m] = av;
      }
      #pragma unroll
      for (int m = 0; m < 4; ++m)
        #pragma unroll
        for (int n = 0; n < 3; ++n)
          acc[m][n] = MFMA(a[m], bw[kk][n], acc[m][n], 0, 0, 0);
    }
    __syncthreads();   // cur-reads done AND next-stage drained
    cur ^= 1;
  }
#undef STAGEX

  // epilogue: C/D layout col=lane&15, row=lg*4+reg
  const int b  = row0 >> 11;
  const int t0 = row0 & 2047;
  #pragma unroll
  for (int m = 0; m < 4; ++m) {
    const int trow = m*16 + lg*4;
    #pragma unroll
    for (int n = 0; n < 3; ++n) {
      const int nbase = w*48 + n*16;
      const int wm = nbase >> 6;            // wave-uniform: 0=k,1=q,2=v
      const int h  = (nbase + lr) & 63;
      if (wm == 2) {
        s16x4 p;
        #pragma unroll
        for (int r = 0; r < 4; ++r) p[r] = f2bf(acc[m][n][r]);
        *(s16x4*)(vt + ((size_t)(b*64 + h)) * SEQ + t0 + trow) = p;
      } else {
        short* dst = (wm == 0) ? kb : qb;
        #pragma unroll
        for (int r = 0; r < 4; ++r)
          dst[(size_t)(row0 + trow + r) * HS + h] = f2bf(acc[m][n][r]);
      }
    }
  }
}

// ---------------------------------------------------------------------------
// Flash attention v10 (R16 form, verbatim -- confirmed win): dbuf q_s/v_s via
// global_load_lds (pre-swizzled global source), one barrier per tile,
// fixed-max softmax, ones-MFMA row-sum, LPT + XCD swizzle, 3 blocks/CU.
// ---------------------------------------------------------------------------
__global__ __launch_bounds__(256, 3) void attn_kernel(
    const short* __restrict__ kb, const short* __restrict__ qb,
    const short* __restrict__ vt, float* __restrict__ out)
{
  __shared__ __align__(16) u16 q_s[2][4096];
  __shared__ __align__(16) u16 v_s[2][4096];
  __shared__ __align__(16) u16 P_lds[4][16][72];   // per-wave private
  const int bid = blockIdx.x;
  const int wg  = (bid & 7) * 128 + (bid >> 3);    // 128 blocks (4 batches)/XCD
  const int b   = wg >> 5;
  const int it  = 31 - (wg & 31);                  // heavy i-tiles first (LPT)
  const int tid = threadIdx.x;
  const int w   = tid >> 6;                        // 0..3 (16-row strip)
  const int lr  = tid & 15;
  const int lg  = (tid & 63) >> 4;
  const int iw0 = it * 64 + w * 16;

  const short* qbb = qb + (size_t)b * SEQ * HS;
  const short* vtb = vt + (size_t)b * 64 * SEQ;

  const int srow0 = (0*256 + tid) >> 3, sc80 = tid & 7;
  const int srow1 = (256 + tid) >> 3;
  const int gcol0 = (sc80 * 8) ^ ((srow0 & 7) << 3);
  const int gcol1 = (sc80 * 8) ^ ((srow1 & 7) << 3);

#define STAGE(BUF, J0) do {                                                    \
    u16* lq0 = &q_s[BUF][(w*64) * 8];                                          \
    u16* lv0 = &v_s[BUF][(w*64) * 8];                                          \
    u16* lq1 = &q_s[BUF][(256 + w*64) * 8];                                    \
    u16* lv1 = &v_s[BUF][(256 + w*64) * 8];                                    \
    gl_lds16(qbb + (size_t)((J0) + srow0) * HS + gcol0, lq0);                  \
    gl_lds16(vtb + (size_t)srow0 * SEQ + (J0) + gcol0, lv0);                   \
    gl_lds16(qbb + (size_t)((J0) + srow1) * HS + gcol1, lq1);                  \
    gl_lds16(vtb + (size_t)srow1 * SEQ + (J0) + gcol1, lv1);                   \
  } while (0)

  s16x8 ones;
  #pragma unroll
  for (int e = 0; e < 8; ++e) ones[e] = (short)0x3F80;   // bf16 1.0

  s16x8 kfrag[2];
  {
    const short* kp = kb + ((size_t)(b*SEQ) + iw0 + lr) * HS + lg*8;
    kfrag[0] = *(const s16x8*)(kp);
    kfrag[1] = *(const s16x8*)(kp + 32);
  }

  f32x4 o[4];
  #pragma unroll
  for (int n = 0; n < 4; ++n) o[n] = f32x4{0.f, 0.f, 0.f, 0.f};
  f32x4 lac = f32x4{0.f, 0.f, 0.f, 0.f};

  STAGE(0, 0);
  __syncthreads();

  int cur = 0;
  #pragma unroll 1
  for (int jt = 0; jt <= it; ++jt) {
    if (jt < it) STAGE(cur ^ 1, (jt + 1) * 64);
    const u16* qsb = q_s[cur];
    const u16* vsb = v_s[cur];
    f32x4 sc[4];
    #pragma unroll
    for (int s = 0; s < 4; ++s) {
      const int row = s*16 + lr, base = row * 64, swz = (row & 7) << 3;
      s16x8 q0 = *(const s16x8*)&qsb[base + ((lg*8) ^ swz)];
      s16x8 q1 = *(const s16x8*)&qsb[base + ((32 + lg*8) ^ swz)];
      f32x4 z = f32x4{0.f, 0.f, 0.f, 0.f};
      z = MFMA(q0, kfrag[0], z, 0, 0, 0);
      z = MFMA(q1, kfrag[1], z, 0, 0, 0);
      sc[s] = z;
    }
    const bool diag = (jt == it);
    #pragma unroll
    for (int s = 0; s < 4; ++s) {
      s16x4 pk;
      #pragma unroll
      for (int r = 0; r < 4; ++r) {
        float e = __expf(fmaf(sc[s][r], 0.03125f, -4.0f));
        if (diag && (s*16 + lg*4 + r > w*16 + lr)) e = 0.f;
        pk[r] = f2bf(e);
      }
      *(s16x4*)&P_lds[w][lr][16*s + 4*lg] = pk;
    }
    s16x8 pA0 = *(const s16x8*)&P_lds[w][lr][8*lg];
    s16x8 pA1 = *(const s16x8*)&P_lds[w][lr][32 + 8*lg];
    __builtin_amdgcn_s_setprio(1);
    #pragma unroll
    for (int n = 0; n < 4; ++n) {
      const int rowh = n*16 + lr, base = rowh * 64, swz = (rowh & 7) << 3;
      s16x8 v0 = *(const s16x8*)&vsb[base + ((lg*8) ^ swz)];
      s16x8 v1 = *(const s16x8*)&vsb[base + ((32 + lg*8) ^ swz)];
      o[n] = MFMA(pA0, v0, o[n], 0, 0, 0);
      o[n] = MFMA(pA1, v1, o[n], 0, 0, 0);
    }
    lac = MFMA(pA0, ones, lac, 0, 0, 0);
    lac = MFMA(pA1, ones, lac, 0, 0, 0);
    __builtin_amdgcn_s_setprio(0);
    __syncthreads();
    cur ^= 1;
  }
#undef STAGE

  float inv[4];
  #pragma unroll
  for (int r = 0; r < 4; ++r) inv[r] = 1.f / lac[r];
  #pragma unroll
  for (int n = 0; n < 4; ++n)
    #pragma unroll
    for (int r = 0; r < 4; ++r)
      out[((size_t)(b*SEQ) + iw0 + lg*4 + r) * HS + n*16 + lr] = o[n][r] * inv[r];
}

extern "C" void kernel_launch(void* const* d_in, const int* in_sizes, int n_in,
                              void* d_out, int out_size, void* d_ws, size_t ws_size,
                              hipStream_t stream) {
  const float* x  = (const float*)d_in[0];
  const float* Wk = (const float*)d_in[1];
  const float* Wq = (const float*)d_in[2];
  const float* Wv = (const float*)d_in[3];
  float* out = (float*)d_out;
  const size_t PLANE = (size_t)BT * HS;          // 4M elements
  short* kb = (short*)d_ws;                      // bf16 [BT][64]
  short* qb = kb + PLANE;                        // bf16 [BT][64]
  short* vt = kb + 2*PLANE;                      // bf16 [B][64][SEQ]
  short* Wt = kb + 3*PLANE;                      // bf16 [192][1024]

  wconv_kernel<<<192, 256, 0, stream>>>(Wk, Wq, Wv, Wt);
  proj_kernel<<<BT/64, 256, 0, stream>>>(x, Wt, kb, qb, vt);
  attn_kernel<<<BATCH*(SEQ/64), 256, 0, stream>>>(kb, qb, vt, out);
}

// Round 20
// 127.043 us; speedup vs baseline: 1.0346x; 1.0346x over previous
//
#include <hip/hip_runtime.h>
#include <hip/hip_bf16.h>

#define BATCH 32
#define SEQ   2048
#define EMB   1024
#define HS    64
#define BT    (BATCH*SEQ)   // 65536 rows

typedef short s16x4 __attribute__((ext_vector_type(4)));
typedef short s16x8 __attribute__((ext_vector_type(8)));
typedef float f32x4 __attribute__((ext_vector_type(4)));
using u16 = unsigned short;

static __device__ __forceinline__ short f2bf(float f) {
  __hip_bfloat16 h = __float2bfloat16(f);
  return *reinterpret_cast<short*>(&h);
}
static __device__ __forceinline__ void gl_lds16(const void* g, void* l) {
  __builtin_amdgcn_global_load_lds(
      (const __attribute__((address_space(1))) unsigned int*)g,
      (__attribute__((address_space(3))) unsigned int*)l, 16, 0, 0);
}

#define MFMA __builtin_amdgcn_mfma_f32_16x16x32_bf16

// ---------------------------------------------------------------------------
// W -> bf16, transposed: Wt[n][k], n = w*64+h (Wk|Wq|Wv). 768 KB once.
// ---------------------------------------------------------------------------
__global__ __launch_bounds__(256) void wconv_kernel(
    const float* __restrict__ Wk, const float* __restrict__ Wq,
    const float* __restrict__ Wv, short* __restrict__ Wt)
{
  const int n = blockIdx.x;            // 0..191
  const int w = n >> 6, h = n & 63;
  const float* Wp = (w == 0) ? Wk : (w == 1) ? Wq : Wv;
  const int k0 = threadIdx.x * 4;
  s16x4 p;
  #pragma unroll
  for (int e = 0; e < 4; ++e) p[e] = f2bf(Wp[(size_t)(k0 + e) * HS + h]);
  *(s16x4*)(Wt + (size_t)n * EMB + k0) = p;
}

// ---------------------------------------------------------------------------
// Projection v6 = R11 form (simplest of the equal-speed variants) +
// PER-BLOCK K-PHASE ROTATION: block starts its K-reduction at
// ((bid&3)*256) and wraps mod 1024. Co-resident blocks (consecutive bids,
// same CU) then touch different x columns on different step clocks ->
// their load-burst / barrier-wait phases interleave instead of aligning
// (convoy desync). Sum order changes; result identical up to fp32 reorder.
// ---------------------------------------------------------------------------
__global__ __launch_bounds__(256, 4) void proj_kernel(
    const float* __restrict__ x, const short* __restrict__ Wt,
    short* __restrict__ kb, short* __restrict__ qb, short* __restrict__ vt)
{
  __shared__ __align__(16) u16 xs[64][72];
  const int tid  = threadIdx.x;
  const int row0 = blockIdx.x * 64;
  const int w  = tid >> 6, l = tid & 63;
  const int lr = l & 15, lg = l >> 4;
  const int kphase = (blockIdx.x & 3) << 8;   // 0,256,512,768

  f32x4 acc[4][3];
  #pragma unroll
  for (int m = 0; m < 4; ++m)
    #pragma unroll
    for (int n = 0; n < 3; ++n) acc[m][n] = f32x4{0.f, 0.f, 0.f, 0.f};

  for (int ks = 0; ks < EMB; ks += 64) {
    const int k0 = (ks + kphase) & (EMB - 1);
    s16x8 bw[2][3];
    #pragma unroll
    for (int kk = 0; kk < 2; ++kk)
      #pragma unroll
      for (int n = 0; n < 3; ++n)
        bw[kk][n] = *(const s16x8*)(Wt + (size_t)(w*48 + n*16 + lr) * EMB + k0 + kk*32 + lg*8);
    __syncthreads();
    #pragma unroll
    for (int i = 0; i < 4; ++i) {
      const int idx = i * 256 + tid;
      const int r = idx >> 4, c4 = idx & 15;
      float4 t = *(const float4*)(x + (size_t)(row0 + r) * EMB + k0 + c4 * 4);
      s16x4 p;
      p[0] = f2bf(t.x); p[1] = f2bf(t.y); p[2] = f2bf(t.z); p[3] = f2bf(t.w);
      *(s16x4*)&xs[r][c4 * 4] = p;
    }
    __syncthreads();
    #pragma unroll
    for (int kk = 0; kk < 2; ++kk) {
      s16x8 a[4];
      #pragma unroll
      for (int m = 0; m < 4; ++m)
        a[m] = *(const s16x8*)&xs[m*16 + lr][kk*32 + lg*8];
      #pragma unroll
      for (int m = 0; m < 4; ++m)
        #pragma unroll
        for (int n = 0; n < 3; ++n)
          acc[m][n] = MFMA(a[m], bw[kk][n], acc[m][n], 0, 0, 0);
    }
  }

  const int b  = row0 >> 11;
  const int t0 = row0 & 2047;
  #pragma unroll
  for (int m = 0; m < 4; ++m) {
    const int trow = m*16 + lg*4;
    #pragma unroll
    for (int n = 0; n < 3; ++n) {
      const int nbase = w*48 + n*16;
      const int wm = nbase >> 6;
      const int h  = (nbase + lr) & 63;
      if (wm == 2) {
        s16x4 p;
        #pragma unroll
        for (int r = 0; r < 4; ++r) p[r] = f2bf(acc[m][n][r]);
        *(s16x4*)(vt + ((size_t)(b*64 + h)) * SEQ + t0 + trow) = p;
      } else {
        short* dst = (wm == 0) ? kb : qb;
        #pragma unroll
        for (int r = 0; r < 4; ++r)
          dst[(size_t)(row0 + trow + r) * HS + h] = f2bf(acc[m][n][r]);
      }
    }
  }
}

// ---------------------------------------------------------------------------
// Flash attention v10 (R16 form, verbatim -- confirmed win): dbuf q_s/v_s via
// global_load_lds (pre-swizzled global source), one barrier per tile,
// fixed-max softmax, ones-MFMA row-sum, LPT + XCD swizzle, 3 blocks/CU.
// ---------------------------------------------------------------------------
__global__ __launch_bounds__(256, 3) void attn_kernel(
    const short* __restrict__ kb, const short* __restrict__ qb,
    const short* __restrict__ vt, float* __restrict__ out)
{
  __shared__ __align__(16) u16 q_s[2][4096];
  __shared__ __align__(16) u16 v_s[2][4096];
  __shared__ __align__(16) u16 P_lds[4][16][72];   // per-wave private
  const int bid = blockIdx.x;
  const int wg  = (bid & 7) * 128 + (bid >> 3);    // 128 blocks (4 batches)/XCD
  const int b   = wg >> 5;
  const int it  = 31 - (wg & 31);                  // heavy i-tiles first (LPT)
  const int tid = threadIdx.x;
  const int w   = tid >> 6;                        // 0..3 (16-row strip)
  const int lr  = tid & 15;
  const int lg  = (tid & 63) >> 4;
  const int iw0 = it * 64 + w * 16;

  const short* qbb = qb + (size_t)b * SEQ * HS;
  const short* vtb = vt + (size_t)b * 64 * SEQ;

  const int srow0 = (0*256 + tid) >> 3, sc80 = tid & 7;
  const int srow1 = (256 + tid) >> 3;
  const int gcol0 = (sc80 * 8) ^ ((srow0 & 7) << 3);
  const int gcol1 = (sc80 * 8) ^ ((srow1 & 7) << 3);

#define STAGE(BUF, J0) do {                                                    \
    u16* lq0 = &q_s[BUF][(w*64) * 8];                                          \
    u16* lv0 = &v_s[BUF][(w*64) * 8];                                          \
    u16* lq1 = &q_s[BUF][(256 + w*64) * 8];                                    \
    u16* lv1 = &v_s[BUF][(256 + w*64) * 8];                                    \
    gl_lds16(qbb + (size_t)((J0) + srow0) * HS + gcol0, lq0);                  \
    gl_lds16(vtb + (size_t)srow0 * SEQ + (J0) + gcol0, lv0);                   \
    gl_lds16(qbb + (size_t)((J0) + srow1) * HS + gcol1, lq1);                  \
    gl_lds16(vtb + (size_t)srow1 * SEQ + (J0) + gcol1, lv1);                   \
  } while (0)

  s16x8 ones;
  #pragma unroll
  for (int e = 0; e < 8; ++e) ones[e] = (short)0x3F80;   // bf16 1.0

  s16x8 kfrag[2];
  {
    const short* kp = kb + ((size_t)(b*SEQ) + iw0 + lr) * HS + lg*8;
    kfrag[0] = *(const s16x8*)(kp);
    kfrag[1] = *(const s16x8*)(kp + 32);
  }

  f32x4 o[4];
  #pragma unroll
  for (int n = 0; n < 4; ++n) o[n] = f32x4{0.f, 0.f, 0.f, 0.f};
  f32x4 lac = f32x4{0.f, 0.f, 0.f, 0.f};

  STAGE(0, 0);
  __syncthreads();

  int cur = 0;
  #pragma unroll 1
  for (int jt = 0; jt <= it; ++jt) {
    if (jt < it) STAGE(cur ^ 1, (jt + 1) * 64);
    const u16* qsb = q_s[cur];
    const u16* vsb = v_s[cur];
    f32x4 sc[4];
    #pragma unroll
    for (int s = 0; s < 4; ++s) {
      const int row = s*16 + lr, base = row * 64, swz = (row & 7) << 3;
      s16x8 q0 = *(const s16x8*)&qsb[base + ((lg*8) ^ swz)];
      s16x8 q1 = *(const s16x8*)&qsb[base + ((32 + lg*8) ^ swz)];
      f32x4 z = f32x4{0.f, 0.f, 0.f, 0.f};
      z = MFMA(q0, kfrag[0], z, 0, 0, 0);
      z = MFMA(q1, kfrag[1], z, 0, 0, 0);
      sc[s] = z;
    }
    const bool diag = (jt == it);
    #pragma unroll
    for (int s = 0; s < 4; ++s) {
      s16x4 pk;
      #pragma unroll
      for (int r = 0; r < 4; ++r) {
        float e = __expf(fmaf(sc[s][r], 0.03125f, -4.0f));
        if (diag && (s*16 + lg*4 + r > w*16 + lr)) e = 0.f;
        pk[r] = f2bf(e);
      }
      *(s16x4*)&P_lds[w][lr][16*s + 4*lg] = pk;
    }
    s16x8 pA0 = *(const s16x8*)&P_lds[w][lr][8*lg];
    s16x8 pA1 = *(const s16x8*)&P_lds[w][lr][32 + 8*lg];
    __builtin_amdgcn_s_setprio(1);
    #pragma unroll
    for (int n = 0; n < 4; ++n) {
      const int rowh = n*16 + lr, base = rowh * 64, swz = (rowh & 7) << 3;
      s16x8 v0 = *(const s16x8*)&vsb[base + ((lg*8) ^ swz)];
      s16x8 v1 = *(const s16x8*)&vsb[base + ((32 + lg*8) ^ swz)];
      o[n] = MFMA(pA0, v0, o[n], 0, 0, 0);
      o[n] = MFMA(pA1, v1, o[n], 0, 0, 0);
    }
    lac = MFMA(pA0, ones, lac, 0, 0, 0);
    lac = MFMA(pA1, ones, lac, 0, 0, 0);
    __builtin_amdgcn_s_setprio(0);
    __syncthreads();
    cur ^= 1;
  }
#undef STAGE

  float inv[4];
  #pragma unroll
  for (int r = 0; r < 4; ++r) inv[r] = 1.f / lac[r];
  #pragma unroll
  for (int n = 0; n < 4; ++n)
    #pragma unroll
    for (int r = 0; r < 4; ++r)
      out[((size_t)(b*SEQ) + iw0 + lg*4 + r) * HS + n*16 + lr] = o[n][r] * inv[r];
}

extern "C" void kernel_launch(void* const* d_in, const int* in_sizes, int n_in,
                              void* d_out, int out_size, void* d_ws, size_t ws_size,
                              hipStream_t stream) {
  const float* x  = (const float*)d_in[0];
  const float* Wk = (const float*)d_in[1];
  const float* Wq = (const float*)d_in[2];
  const float* Wv = (const float*)d_in[3];
  float* out = (float*)d_out;
  const size_t PLANE = (size_t)BT * HS;          // 4M elements
  short* kb = (short*)d_ws;                      // bf16 [BT][64]
  short* qb = kb + PLANE;                        // bf16 [BT][64]
  short* vt = kb + 2*PLANE;                      // bf16 [B][64][SEQ]
  short* Wt = kb + 3*PLANE;                      // bf16 [192][1024]

  wconv_kernel<<<192, 256, 0, stream>>>(Wk, Wq, Wv, Wt);
  proj_kernel<<<BT/64, 256, 0, stream>>>(x, Wt, kb, qb, vt);
  attn_kernel<<<BATCH*(SEQ/64), 256, 0, stream>>>(kb, qb, vt, out);
}